// Round 11
// baseline (124.291 us; speedup 1.0000x reference)
//
#include <hip/hip_runtime.h>
#include <math.h>

// B=4096, S=128, F=8, H1=64, H2=32
// Stage 0: x16 = fp16(x)                          (elementwise, once)
// Stage A: x1u = fp16(relu(concat(x,time) @ Wc^T + bc)), fp16 MFMA, BM=BN=128, dbuf
// Stage B: fused LSTM1 || LSTM2(lag-1), 8 waves (2/SIMD), fp16 MFMA,
//          log2e-prescaled weights (g-gate 2x), fused-rcp c-update, pkrtz.

typedef _Float16 f16x8 __attribute__((ext_vector_type(8)));
typedef float f32x4 __attribute__((ext_vector_type(4)));

union H8 { uint4 q; _Float16 h[8]; f16x8 v; };

#define MF(A, B, C) __builtin_amdgcn_mfma_f32_16x16x32_f16(A, B, C, 0, 0, 0)
#define LOG2E 1.44269504f

__device__ __forceinline__ float sigm_pre(float y) {
  return __builtin_amdgcn_rcpf(1.f + __builtin_amdgcn_exp2f(-y));
}
__device__ __forceinline__ float tanh_raw(float c) {
  return 1.f - 2.f * __builtin_amdgcn_rcpf(1.f + __builtin_amdgcn_exp2f(c * 2.88539008f));
}
// fused c-update: c' = sig(yf)*c + sig(yi)*tanh(yg2/2ln2), one rcp.
__device__ __forceinline__ float lstm_c(float yi, float yf, float yg2, float cold) {
  float Ei = __builtin_amdgcn_exp2f(-yi);
  float Ef = __builtin_amdgcn_exp2f(-yf);
  float Eg = __builtin_amdgcn_exp2f(yg2);
  float Pf = 1.f + Ef;
  float t1 = (1.f + Ei) * (1.f + Eg);
  float num = fmaf(Eg - 1.f, Pf, cold * t1);
  return num * __builtin_amdgcn_rcpf(Pf * t1);
}
__device__ __forceinline__ unsigned pkrtz(float a, float b) {
  return __builtin_bit_cast(unsigned, __builtin_amdgcn_cvt_pkrtz(a, b));
}

// ---------------- Kernel 0: x -> fp16, once ----------------------------------
__global__ __launch_bounds__(256) void cvt_x(
    const float* __restrict__ x, unsigned* __restrict__ x16)
{
  const int idx = blockIdx.x * 256 + threadIdx.x;  // 524288 threads, 8 f32 each
  const float4* src = (const float4*)x;
  float4 a = src[2 * idx], b = src[2 * idx + 1];
  uint4 o = {pkrtz(a.x, a.y), pkrtz(a.z, a.w), pkrtz(b.x, b.y), pkrtz(b.z, b.w)};
  ((uint4*)x16)[idx] = o;
}

// ---------------- Kernel A: combine GEMM, fp16 MFMA, BM=BN=128, dbuf ---------
// M=4096 x N=1024 x K=1024 (+time col + bias + relu). 512 thr, 8 waves (4m x 2n).
#define CROW 72  // fp16 slots per staged row (64 + 8 pad) = 144 B

__global__ __launch_bounds__(512, 1) void combine_mfma(
    const _Float16* __restrict__ xh, const float* __restrict__ tme,
    const float* __restrict__ Wc, const float* __restrict__ bc,
    unsigned* __restrict__ x1u)   // fp16 pairs: [4096][512] u32
{
  extern __shared__ __align__(16) char smraw[];
  _Float16 (*sA)[128][CROW] = (_Float16 (*)[128][CROW])(smraw);            // 36864
  _Float16 (*sB)[128][CROW] = (_Float16 (*)[128][CROW])(smraw + 36864);    // 36864
  float* sT  = (float*)(smraw + 73728);   // [128]
  float* sWl = (float*)(smraw + 74240);   // [128]
  float* sBc = (float*)(smraw + 74752);   // [128]
  _Float16 (*Cst)[136] = (_Float16 (*)[136])smraw;  // epilogue overlay, 34816

  const int tid = threadIdx.x;
  const int lane = tid & 63;
  const int w = tid >> 6;
  const int wm = w & 3, wn = w >> 2;
  const int r = lane & 15, grp = lane >> 4;
  const int M0 = blockIdx.y * 128, N0 = blockIdx.x * 128;

  if (tid < 128) sT[tid] = tme[M0 + tid];
  else if (tid < 256) sWl[tid - 128] = Wc[(size_t)(N0 + tid - 128) * 1025 + 1024];
  else if (tid < 384) sBc[tid - 256] = bc[N0 + tid - 256];

#define STAGE_A(KT, BUF)                                                       \
  _Pragma("unroll") for (int i = 0; i < 2; ++i) {                              \
    int idx = tid + i * 512;                                                   \
    int row = idx >> 3, c8 = idx & 7;                                          \
    uint4 v = *(const uint4*)&xh[(size_t)(M0 + row) * 1024 + (KT) + c8 * 8];   \
    *(uint4*)&sA[BUF][row][c8 * 8] = v;                                        \
  }
#define STAGE_B(KT, BUF)                                                       \
  _Pragma("unroll") for (int i = 0; i < 4; ++i) {                              \
    int idx = tid + i * 512;                                                   \
    int row = idx >> 4, kq = idx & 15;                                         \
    float4 v = *(const float4*)&Wc[(size_t)(N0 + row) * 1025 + (KT) + kq * 4]; \
    *(uint2*)&sB[BUF][row][kq * 4] = uint2{pkrtz(v.x, v.y), pkrtz(v.z, v.w)};  \
  }

  f32x4 acc[2][4];
#pragma unroll
  for (int i = 0; i < 2; ++i)
#pragma unroll
    for (int j = 0; j < 4; ++j) acc[i][j] = f32x4{0.f, 0.f, 0.f, 0.f};

  STAGE_A(0, 0);
  STAGE_B(0, 0);
  __syncthreads();

  int cur = 0;
  for (int kt = 0; kt < 1024; kt += 64) {
    H8 af[2][2], bf[4][2];
#pragma unroll
    for (int i = 0; i < 2; ++i)
#pragma unroll
      for (int c = 0; c < 2; ++c)
        af[i][c].q = *(const uint4*)&sA[cur][wm * 32 + i * 16 + r][c * 32 + grp * 8];
#pragma unroll
    for (int j = 0; j < 4; ++j)
#pragma unroll
      for (int c = 0; c < 2; ++c)
        bf[j][c].q = *(const uint4*)&sB[cur][wn * 64 + j * 16 + r][c * 32 + grp * 8];

    if (kt < 960) {
      STAGE_A(kt + 64, cur ^ 1);
      STAGE_B(kt + 64, cur ^ 1);
    }

#pragma unroll
    for (int i = 0; i < 2; ++i)
#pragma unroll
      for (int j = 0; j < 4; ++j) {
        acc[i][j] = MF(af[i][0].v, bf[j][0].v, acc[i][j]);
        acc[i][j] = MF(af[i][1].v, bf[j][1].v, acc[i][j]);
      }
    __syncthreads();
    cur ^= 1;
  }
#undef STAGE_A
#undef STAGE_B

  // epilogue: time col + bias + relu -> fp16 -> LDS transpose -> coalesced store
#pragma unroll
  for (int i = 0; i < 2; ++i) {
#pragma unroll
    for (int j = 0; j < 4; ++j) {
      int n = wn * 64 + j * 16 + r;
      float wl = sWl[n], bv = sBc[n];
#pragma unroll
      for (int q = 0; q < 4; ++q) {
        int mm = wm * 32 + i * 16 + 4 * grp + q;
        float v = acc[i][j][q] + sT[mm] * wl + bv;
        Cst[mm][n] = (_Float16)fmaxf(v, 0.f);
      }
    }
  }
  __syncthreads();
#pragma unroll
  for (int i = 0; i < 4; ++i) {   // 128 rows x 16 uint4 = 2048 uint4
    int idx = tid + i * 512;
    int row = idx >> 4, c4 = idx & 15;
    uint4 v = *(const uint4*)&Cst[row][c4 * 8];
    *(uint4*)&x1u[(size_t)(M0 + row) * 512 + (N0 >> 1) + c4 * 4] = v;
  }
}

// ---------------- Kernel B: fused LSTM fp16, 8 waves, lag-1 L2 --------------
// wave w: vw = w>>1, wsub = w&1.
// L1: tiles jj=0,1 -> h1 = vw*16 + 4*grp + 2*wsub + jj.
// L2: tile u = 2*vw + wsub -> h2 = 4*u + grp.
#define ROW1 72   // shorts per sh1 row: 64 h1 slots + 8 pad
#define ROW2 40   // shorts per sh2 row: 32 h2 slots + 8 pad

__global__ __launch_bounds__(512, 2) void lstm_fused_mfma(
    const unsigned* __restrict__ x1u,
    const float* __restrict__ Wih1, const float* __restrict__ Whh1,
    const float* __restrict__ Wih2, const float* __restrict__ Whh2,
    const float* __restrict__ bih2, const float* __restrict__ bhh2,
    const float* __restrict__ Wout, const float* __restrict__ bout,
    float* __restrict__ out)
{
  __shared__ __align__(16) unsigned sxw[128 * 16 * 4];       // fp16 x [t][b][4u32] 32KB
  __shared__ float sWoT[32 * 132];                           // Wout^T [h2][t+pad] 16896B
  __shared__ __align__(16) unsigned short sh1[2][16][ROW1];  // 4608B
  __shared__ __align__(16) unsigned short sh2[2][16][ROW2];  // 2560B
  __shared__ float sOut[8][16];

  const int tid = threadIdx.x;
  const int lane = tid & 63;
  const int w = tid >> 6;       // wave 0..7
  const int vw = w >> 1;
  const int wsub = w & 1;
  const int col = lane & 15;    // A-row at pack time / batch col at run time
  const int grp = lane >> 4;    // k-slot group; C rows 4*grp+r (r = gate)
  const int b0 = blockIdx.x * 16;

  // ---- pack fp16 A-side weight fragments (once) ----
  // gate rows: i,f,o scaled by log2e; g-gate rows by 2*log2e.
  const int m1 = col >> 2, g1 = col & 3;  // A row = 4*m + gate
  const float gsc = (g1 == 2) ? 2.f * LOG2E : LOG2E;
  f16x8 A1h[2][2];  // L1 tiles jj: Whh1 chunks c=0,1 (k=64)
  f16x8 A1x[2];     // L1 tiles jj: Wih1 chunk (8 of 32 k-slots)
#pragma unroll
  for (int jj = 0; jj < 2; ++jj) {
    const int wr = g1 * 64 + vw * 16 + 4 * m1 + (2 * wsub + jj);
#pragma unroll
    for (int c = 0; c < 2; ++c) {
      H8 f;
#pragma unroll
      for (int q = 0; q < 8; ++q)
        f.h[q] = (_Float16)(Whh1[wr * 64 + c * 32 + grp * 8 + q] * gsc);
      A1h[jj][c] = f.v;
    }
    H8 fx;
#pragma unroll
    for (int q = 0; q < 8; ++q)
      fx.h[q] = (grp == 0) ? (_Float16)(Wih1[wr * 8 + q] * gsc) : (_Float16)0.f;
    A1x[jj] = fx.v;
  }
  f16x8 A2[3];  // L2: c0,c1 = Wih2 (k=64), c2 = Whh2 (k=32)
  const int u = 2 * vw + wsub;
  {
    const int wr = g1 * 32 + 4 * u + m1;
#pragma unroll
    for (int c = 0; c < 3; ++c) {
      H8 f;
#pragma unroll
      for (int q = 0; q < 8; ++q) {
        float wv = (c < 2) ? Wih2[wr * 64 + c * 32 + grp * 8 + q]
                           : Whh2[wr * 32 + grp * 8 + q];
        f.h[q] = (_Float16)(wv * gsc);
      }
      A2[c] = f.v;
    }
  }
  const int h2o = 4 * u + grp;
  f32x4 b2q;
#pragma unroll
  for (int r = 0; r < 4; ++r) {
    const float rs = (r == 2) ? 2.f * LOG2E : LOG2E;
    b2q[r] = (bih2[r * 32 + h2o] + bhh2[r * 32 + h2o]) * rs;
  }
  const f32x4 zq = {0.f, 0.f, 0.f, 0.f};

  // ---- LDS init ----
  for (int idx = tid; idx < 4096; idx += 512) {  // Wout -> [h2][t], stride 132
    int t = idx >> 5, h = idx & 31;
    sWoT[h * 132 + t] = Wout[idx];
  }
  {
    unsigned short* z = &sh1[0][0][0];
    for (int i2 = tid; i2 < 2 * 16 * ROW1; i2 += 512) z[i2] = 0;
    unsigned short* z2 = &sh2[0][0][0];
    for (int i2 = tid; i2 < 2 * 16 * ROW2; i2 += 512) z2[i2] = 0;
  }
  for (int idx = tid; idx < 16 * 512; idx += 512) {  // x preload: [t][b][4u32]
    int bb = idx >> 9, rem = idx & 511;
    int t = rem >> 2, pr = rem & 3;
    sxw[t * 64 + bb * 4 + pr] = x1u[(size_t)(b0 + bb) * 512 + rem];
  }
  __syncthreads();

  float c1a = 0.f, c1b = 0.f, c2 = 0.f, accO = 0.f;

#define PHASE(T, CUR, DO_L1, DO_L2)                                            \
  {                                                                            \
    H8 s0, s1, s2;                                                             \
    s0.q = *(const uint4*)&sh1[CUR][col][grp * 8];                             \
    s1.q = *(const uint4*)&sh1[CUR][col][32 + grp * 8];                        \
    s2.q = *(const uint4*)&sh2[CUR][col][grp * 8];                             \
    if (DO_L2) {                                                               \
      const float won = sWoT[h2o * 132 + (T) - 1];                             \
      f32x4 a = MF(A2[2], s2.v, b2q);                                          \
      a = MF(A2[0], s0.v, a);                                                  \
      a = MF(A2[1], s1.v, a);                                                  \
      float cc = lstm_c(a[0], a[1], a[2], c2);                                 \
      c2 = cc;                                                                 \
      float hn = sigm_pre(a[3]) * tanh_raw(cc);                                \
      accO = fmaf(hn, won, accO);                                              \
      *(_Float16*)&sh2[(CUR) ^ 1][col][h2o] = (_Float16)hn;                    \
    }                                                                          \
    if (DO_L1) {                                                               \
      H8 sx;                                                                   \
      sx.q = *(const uint4*)&sxw[(T) * 64 + col * 4];                          \
      f32x4 a0 = MF(A1x[0], sx.v, zq);                                         \
      f32x4 a1 = MF(A1x[1], sx.v, zq);                                         \
      a0 = MF(A1h[0][0], s0.v, a0);                                            \
      a1 = MF(A1h[1][0], s0.v, a1);                                            \
      a0 = MF(A1h[0][1], s1.v, a0);                                            \
      a1 = MF(A1h[1][1], s1.v, a1);                                            \
      float cc0 = lstm_c(a0[0], a0[1], a0[2], c1a);                            \
      c1a = cc0;                                                               \
      float h0 = sigm_pre(a0[3]) * tanh_raw(cc0);                              \
      float cc1 = lstm_c(a1[0], a1[1], a1[2], c1b);                            \
      c1b = cc1;                                                               \
      float h1v = sigm_pre(a1[3]) * tanh_raw(cc1);                             \
      *(unsigned*)&sh1[(CUR) ^ 1][col][vw * 16 + 4 * grp + 2 * wsub] =         \
          pkrtz(h0, h1v);                                                      \
    }                                                                          \
    __syncthreads();                                                           \
  }

  PHASE(0, 0, true, false);
  PHASE(1, 1, true, true);
  for (int tt = 1; tt < 64; ++tt) {
    const int t0 = 2 * tt;
    PHASE(t0, 0, true, true);
    PHASE(t0 + 1, 1, true, true);
  }
  PHASE(128, 0, false, true);
#undef PHASE

  // ---- output reduce: over grp (16/32 shuffles) then 8 waves ----
  accO += __shfl_xor(accO, 16);
  accO += __shfl_xor(accO, 32);
  if (grp == 0) sOut[u][col] = accO;
  __syncthreads();
  if (tid < 16) {
    float s = bout[0];
#pragma unroll
    for (int q = 0; q < 8; ++q) s += sOut[q][tid];
    out[b0 + tid] = s;
  }
}

extern "C" void kernel_launch(void* const* d_in, const int* in_sizes, int n_in,
                              void* d_out, int out_size, void* d_ws, size_t ws_size,
                              hipStream_t stream) {
  const float* x    = (const float*)d_in[0];
  const float* tme  = (const float*)d_in[1];
  const float* Wc   = (const float*)d_in[2];
  const float* bc   = (const float*)d_in[3];
  const float* Wih1 = (const float*)d_in[4];
  const float* Whh1 = (const float*)d_in[5];
  const float* Wih2 = (const float*)d_in[6];
  const float* Whh2 = (const float*)d_in[7];
  const float* bih2 = (const float*)d_in[8];
  const float* bhh2 = (const float*)d_in[9];
  const float* Wout = (const float*)d_in[10];
  const float* bout = (const float*)d_in[11];
  float* outp = (float*)d_out;
  unsigned* x1u = (unsigned*)d_ws;            // [4096][512] u32 = 8.39 MB
  unsigned* x16 = x1u + (size_t)4096 * 512;   // [4096][512] u32 = 8.39 MB

  cvt_x<<<2048, 256, 0, stream>>>(x, x16);

  const size_t smemA = 75264;
  hipFuncSetAttribute(reinterpret_cast<const void*>(combine_mfma),
                      hipFuncAttributeMaxDynamicSharedMemorySize, (int)smemA);
  dim3 gA(8, 32);  // N/128, M/128
  combine_mfma<<<gA, 512, smemA, stream>>>((const _Float16*)x16, tme, Wc, bc, x1u);
  lstm_fused_mfma<<<256, 512, 0, stream>>>(x1u, Wih1, Whh1, Wih2, Whh2,
                                           bih2, bhh2, Wout, bout, outp);
}

// Round 12
// 102.624 us; speedup vs baseline: 1.2111x; 1.2111x over previous
//
#include <hip/hip_runtime.h>
#include <math.h>

// B=4096, S=128, F=8, H1=64, H2=32
// Stage 0: x16 = fp16(x)                          (elementwise, once)
// Stage A: x1u = fp16(relu(concat(x,time) @ Wc^T + bc)), fp16 MFMA, BN=64, dbuf,
//          XCD-aware block swizzle (each XCD owns 4 M-panels x all N-panels)
// Stage B: fused LSTM1 || LSTM2(lag-1), 8 waves (2/SIMD), fp16 MFMA,
//          log2e-prescaled weights (g-gate 2x), fused-rcp c-update, pkrtz.

typedef _Float16 f16x8 __attribute__((ext_vector_type(8)));
typedef float f32x4 __attribute__((ext_vector_type(4)));

union H8 { uint4 q; _Float16 h[8]; f16x8 v; };

#define MF(A, B, C) __builtin_amdgcn_mfma_f32_16x16x32_f16(A, B, C, 0, 0, 0)
#define LOG2E 1.44269504f

__device__ __forceinline__ float sigm_pre(float y) {
  return __builtin_amdgcn_rcpf(1.f + __builtin_amdgcn_exp2f(-y));
}
__device__ __forceinline__ float tanh_raw(float c) {
  return 1.f - 2.f * __builtin_amdgcn_rcpf(1.f + __builtin_amdgcn_exp2f(c * 2.88539008f));
}
// fused c-update: c' = sig(yf)*c + sig(yi)*tanh(yg2/2ln2), one rcp.
__device__ __forceinline__ float lstm_c(float yi, float yf, float yg2, float cold) {
  float Ei = __builtin_amdgcn_exp2f(-yi);
  float Ef = __builtin_amdgcn_exp2f(-yf);
  float Eg = __builtin_amdgcn_exp2f(yg2);
  float Pf = 1.f + Ef;
  float t1 = (1.f + Ei) * (1.f + Eg);
  float num = fmaf(Eg - 1.f, Pf, cold * t1);
  return num * __builtin_amdgcn_rcpf(Pf * t1);
}
__device__ __forceinline__ unsigned pkrtz(float a, float b) {
  return __builtin_bit_cast(unsigned, __builtin_amdgcn_cvt_pkrtz(a, b));
}

// ---------------- Kernel 0: x -> fp16, once ----------------------------------
__global__ __launch_bounds__(256) void cvt_x(
    const float* __restrict__ x, unsigned* __restrict__ x16)
{
  const int idx = blockIdx.x * 256 + threadIdx.x;  // 524288 threads, 8 f32 each
  const float4* src = (const float4*)x;
  float4 a = src[2 * idx], b = src[2 * idx + 1];
  uint4 o = {pkrtz(a.x, a.y), pkrtz(a.z, a.w), pkrtz(b.x, b.y), pkrtz(b.z, b.w)};
  ((uint4*)x16)[idx] = o;
}

// ---------------- Kernel A: combine GEMM, fp16 MFMA, dbuf, XCD swizzle -------
// M=4096 x N=1024 x K=1024 (+time col + bias + relu). BM=128 BN=64 BK=64.
// 512 blocks 1D: xcd = bid&7 owns M-panels {4*xcd..4*xcd+3} x all 16 N-panels.
#define CROW 72  // fp16 slots per staged row (64 + 8 pad) = 144 B

__global__ __launch_bounds__(256, 2) void combine_mfma(
    const _Float16* __restrict__ xh, const float* __restrict__ tme,
    const float* __restrict__ Wc, const float* __restrict__ bc,
    unsigned* __restrict__ x1u)   // fp16 pairs: [4096][512] u32
{
  __shared__ __align__(16) _Float16 sA[2][128][CROW];  // 36864 B
  __shared__ __align__(16) _Float16 sB[2][64][CROW];   // 18432 B
  __shared__ float sT[128];
  __shared__ float sWl[64];
  __shared__ float sBc[64];
  _Float16 (*Cst)[CROW] = sA[0];  // epilogue overlay

  const int tid = threadIdx.x;
  const int lane = tid & 63;
  const int w = tid >> 6;
  const int r = lane & 15, grp = lane >> 4;
  // XCD-aware decode: consecutive bids round-robin XCDs (bid&7 = XCD).
  const int bid = blockIdx.x;
  const int xcd = bid & 7, j = bid >> 3;
  const int M0 = (xcd * 4 + (j & 3)) * 128;   // M-panel 0..31
  const int N0 = (j >> 2) * 64;               // N-panel 0..15

  if (tid < 128) sT[tid] = tme[M0 + tid];
  else if (tid < 192) sWl[tid - 128] = Wc[(size_t)(N0 + tid - 128) * 1025 + 1024];
  else sBc[tid - 192] = bc[N0 + tid - 192];

#define STAGE_A(KT, BUF)                                                       \
  _Pragma("unroll") for (int i = 0; i < 4; ++i) {                              \
    int idx = tid + i * 256;                                                   \
    int row = idx >> 3, kq = idx & 7;                                          \
    uint4 v = *(const uint4*)&xh[(size_t)(M0 + row) * 1024 + (KT) + kq * 8];   \
    *(uint4*)&sA[BUF][row][kq * 8] = v;                                        \
  }
#define STAGE_B(KT, BUF)                                                       \
  _Pragma("unroll") for (int i = 0; i < 4; ++i) {                              \
    int idx = tid + i * 256;                                                   \
    int row = idx >> 4, kq = idx & 15;                                         \
    float4 v = *(const float4*)&Wc[(size_t)(N0 + row) * 1025 + (KT) + kq * 4]; \
    *(uint2*)&sB[BUF][row][kq * 4] = uint2{pkrtz(v.x, v.y), pkrtz(v.z, v.w)};  \
  }

  f32x4 acc[2][4];
#pragma unroll
  for (int i = 0; i < 2; ++i)
#pragma unroll
    for (int j2 = 0; j2 < 4; ++j2) acc[i][j2] = f32x4{0.f, 0.f, 0.f, 0.f};

  STAGE_A(0, 0);
  STAGE_B(0, 0);
  __syncthreads();

  int cur = 0;
  for (int kt = 0; kt < 1024; kt += 64) {
    H8 af[2][2], bf[4][2];
#pragma unroll
    for (int i = 0; i < 2; ++i)
#pragma unroll
      for (int c = 0; c < 2; ++c)
        af[i][c].q = *(const uint4*)&sA[cur][w * 32 + i * 16 + r][c * 32 + grp * 8];
#pragma unroll
    for (int j2 = 0; j2 < 4; ++j2)
#pragma unroll
      for (int c = 0; c < 2; ++c)
        bf[j2][c].q = *(const uint4*)&sB[cur][j2 * 16 + r][c * 32 + grp * 8];

    if (kt < 960) {
      STAGE_A(kt + 64, cur ^ 1);
      STAGE_B(kt + 64, cur ^ 1);
    }

#pragma unroll
    for (int i = 0; i < 2; ++i)
#pragma unroll
      for (int j2 = 0; j2 < 4; ++j2) {
        acc[i][j2] = MF(af[i][0].v, bf[j2][0].v, acc[i][j2]);
        acc[i][j2] = MF(af[i][1].v, bf[j2][1].v, acc[i][j2]);
      }
    __syncthreads();
    cur ^= 1;
  }
#undef STAGE_A
#undef STAGE_B

  // epilogue: time col + bias + relu -> fp16 -> LDS transpose -> coalesced store
#pragma unroll
  for (int i = 0; i < 2; ++i) {
#pragma unroll
    for (int j2 = 0; j2 < 4; ++j2) {
      int n = j2 * 16 + r;
      float wl = sWl[n], bv = sBc[n];
#pragma unroll
      for (int q = 0; q < 4; ++q) {
        int mm = w * 32 + i * 16 + 4 * grp + q;
        float v = acc[i][j2][q] + sT[mm] * wl + bv;
        Cst[mm][n] = (_Float16)fmaxf(v, 0.f);
      }
    }
  }
  __syncthreads();
#pragma unroll
  for (int i = 0; i < 4; ++i) {   // 128 rows x 8 uint4 = 1024 uint4
    int idx = tid + i * 256;
    int row = idx >> 3, c8 = idx & 7;
    uint4 v = *(const uint4*)&Cst[row][c8 * 8];
    *(uint4*)&x1u[(size_t)(M0 + row) * 512 + (N0 >> 1) + c8 * 4] = v;
  }
}

// ---------------- Kernel B: fused LSTM fp16, 8 waves, lag-1 L2 --------------
// wave w: vw = w>>1, wsub = w&1.
// L1: tiles jj=0,1 -> h1 = vw*16 + 4*grp + 2*wsub + jj.
// L2: tile u = 2*vw + wsub -> h2 = 4*u + grp.
#define ROW1 72   // shorts per sh1 row: 64 h1 slots + 8 pad
#define ROW2 40   // shorts per sh2 row: 32 h2 slots + 8 pad

__global__ __launch_bounds__(512, 2) void lstm_fused_mfma(
    const unsigned* __restrict__ x1u,
    const float* __restrict__ Wih1, const float* __restrict__ Whh1,
    const float* __restrict__ Wih2, const float* __restrict__ Whh2,
    const float* __restrict__ bih2, const float* __restrict__ bhh2,
    const float* __restrict__ Wout, const float* __restrict__ bout,
    float* __restrict__ out)
{
  __shared__ __align__(16) unsigned sxw[128 * 16 * 4];       // fp16 x [t][b][4u32] 32KB
  __shared__ float sWoT[32 * 132];                           // Wout^T [h2][t+pad] 16896B
  __shared__ __align__(16) unsigned short sh1[2][16][ROW1];  // 4608B
  __shared__ __align__(16) unsigned short sh2[2][16][ROW2];  // 2560B
  __shared__ float sOut[8][16];

  const int tid = threadIdx.x;
  const int lane = tid & 63;
  const int w = tid >> 6;       // wave 0..7
  const int vw = w >> 1;
  const int wsub = w & 1;
  const int col = lane & 15;    // A-row at pack time / batch col at run time
  const int grp = lane >> 4;    // k-slot group; C rows 4*grp+r (r = gate)
  const int b0 = blockIdx.x * 16;

  // ---- pack fp16 A-side weight fragments (once) ----
  // gate rows: i,f,o scaled by log2e; g-gate rows by 2*log2e.
  const int m1 = col >> 2, g1 = col & 3;  // A row = 4*m + gate
  const float gsc = (g1 == 2) ? 2.f * LOG2E : LOG2E;
  f16x8 A1h[2][2];  // L1 tiles jj: Whh1 chunks c=0,1 (k=64)
  f16x8 A1x[2];     // L1 tiles jj: Wih1 chunk (8 of 32 k-slots)
#pragma unroll
  for (int jj = 0; jj < 2; ++jj) {
    const int wr = g1 * 64 + vw * 16 + 4 * m1 + (2 * wsub + jj);
#pragma unroll
    for (int c = 0; c < 2; ++c) {
      H8 f;
#pragma unroll
      for (int q = 0; q < 8; ++q)
        f.h[q] = (_Float16)(Whh1[wr * 64 + c * 32 + grp * 8 + q] * gsc);
      A1h[jj][c] = f.v;
    }
    H8 fx;
#pragma unroll
    for (int q = 0; q < 8; ++q)
      fx.h[q] = (grp == 0) ? (_Float16)(Wih1[wr * 8 + q] * gsc) : (_Float16)0.f;
    A1x[jj] = fx.v;
  }
  f16x8 A2[3];  // L2: c0,c1 = Wih2 (k=64), c2 = Whh2 (k=32)
  const int u = 2 * vw + wsub;
  {
    const int wr = g1 * 32 + 4 * u + m1;
#pragma unroll
    for (int c = 0; c < 3; ++c) {
      H8 f;
#pragma unroll
      for (int q = 0; q < 8; ++q) {
        float wv = (c < 2) ? Wih2[wr * 64 + c * 32 + grp * 8 + q]
                           : Whh2[wr * 32 + grp * 8 + q];
        f.h[q] = (_Float16)(wv * gsc);
      }
      A2[c] = f.v;
    }
  }
  const int h2o = 4 * u + grp;
  f32x4 b2q;
#pragma unroll
  for (int r = 0; r < 4; ++r) {
    const float rs = (r == 2) ? 2.f * LOG2E : LOG2E;
    b2q[r] = (bih2[r * 32 + h2o] + bhh2[r * 32 + h2o]) * rs;
  }
  const f32x4 zq = {0.f, 0.f, 0.f, 0.f};

  // ---- LDS init ----
  for (int idx = tid; idx < 4096; idx += 512) {  // Wout -> [h2][t], stride 132
    int t = idx >> 5, h = idx & 31;
    sWoT[h * 132 + t] = Wout[idx];
  }
  {
    unsigned short* z = &sh1[0][0][0];
    for (int i2 = tid; i2 < 2 * 16 * ROW1; i2 += 512) z[i2] = 0;
    unsigned short* z2 = &sh2[0][0][0];
    for (int i2 = tid; i2 < 2 * 16 * ROW2; i2 += 512) z2[i2] = 0;
  }
  for (int idx = tid; idx < 16 * 512; idx += 512) {  // x preload: [t][b][4u32]
    int bb = idx >> 9, rem = idx & 511;
    int t = rem >> 2, pr = rem & 3;
    sxw[t * 64 + bb * 4 + pr] = x1u[(size_t)(b0 + bb) * 512 + rem];
  }
  __syncthreads();

  float c1a = 0.f, c1b = 0.f, c2 = 0.f, accO = 0.f;

#define PHASE(T, CUR, DO_L1, DO_L2)                                            \
  {                                                                            \
    H8 s0, s1, s2;                                                             \
    s0.q = *(const uint4*)&sh1[CUR][col][grp * 8];                             \
    s1.q = *(const uint4*)&sh1[CUR][col][32 + grp * 8];                        \
    s2.q = *(const uint4*)&sh2[CUR][col][grp * 8];                             \
    if (DO_L2) {                                                               \
      const float won = sWoT[h2o * 132 + (T) - 1];                             \
      f32x4 a = MF(A2[2], s2.v, b2q);                                          \
      a = MF(A2[0], s0.v, a);                                                  \
      a = MF(A2[1], s1.v, a);                                                  \
      float cc = lstm_c(a[0], a[1], a[2], c2);                                 \
      c2 = cc;                                                                 \
      float hn = sigm_pre(a[3]) * tanh_raw(cc);                                \
      accO = fmaf(hn, won, accO);                                              \
      *(_Float16*)&sh2[(CUR) ^ 1][col][h2o] = (_Float16)hn;                    \
    }                                                                          \
    if (DO_L1) {                                                               \
      H8 sx;                                                                   \
      sx.q = *(const uint4*)&sxw[(T) * 64 + col * 4];                          \
      f32x4 a0 = MF(A1x[0], sx.v, zq);                                         \
      f32x4 a1 = MF(A1x[1], sx.v, zq);                                         \
      a0 = MF(A1h[0][0], s0.v, a0);                                            \
      a1 = MF(A1h[1][0], s0.v, a1);                                            \
      a0 = MF(A1h[0][1], s1.v, a0);                                            \
      a1 = MF(A1h[1][1], s1.v, a1);                                            \
      float cc0 = lstm_c(a0[0], a0[1], a0[2], c1a);                            \
      c1a = cc0;                                                               \
      float h0 = sigm_pre(a0[3]) * tanh_raw(cc0);                              \
      float cc1 = lstm_c(a1[0], a1[1], a1[2], c1b);                            \
      c1b = cc1;                                                               \
      float h1v = sigm_pre(a1[3]) * tanh_raw(cc1);                             \
      *(unsigned*)&sh1[(CUR) ^ 1][col][vw * 16 + 4 * grp + 2 * wsub] =         \
          pkrtz(h0, h1v);                                                      \
    }                                                                          \
    __syncthreads();                                                           \
  }

  PHASE(0, 0, true, false);
  PHASE(1, 1, true, true);
  for (int tt = 1; tt < 64; ++tt) {
    const int t0 = 2 * tt;
    PHASE(t0, 0, true, true);
    PHASE(t0 + 1, 1, true, true);
  }
  PHASE(128, 0, false, true);
#undef PHASE

  // ---- output reduce: over grp (16/32 shuffles) then 8 waves ----
  accO += __shfl_xor(accO, 16);
  accO += __shfl_xor(accO, 32);
  if (grp == 0) sOut[u][col] = accO;
  __syncthreads();
  if (tid < 16) {
    float s = bout[0];
#pragma unroll
    for (int q = 0; q < 8; ++q) s += sOut[q][tid];
    out[b0 + tid] = s;
  }
}

extern "C" void kernel_launch(void* const* d_in, const int* in_sizes, int n_in,
                              void* d_out, int out_size, void* d_ws, size_t ws_size,
                              hipStream_t stream) {
  const float* x    = (const float*)d_in[0];
  const float* tme  = (const float*)d_in[1];
  const float* Wc   = (const float*)d_in[2];
  const float* bc   = (const float*)d_in[3];
  const float* Wih1 = (const float*)d_in[4];
  const float* Whh1 = (const float*)d_in[5];
  const float* Wih2 = (const float*)d_in[6];
  const float* Whh2 = (const float*)d_in[7];
  const float* bih2 = (const float*)d_in[8];
  const float* bhh2 = (const float*)d_in[9];
  const float* Wout = (const float*)d_in[10];
  const float* bout = (const float*)d_in[11];
  float* outp = (float*)d_out;
  unsigned* x1u = (unsigned*)d_ws;            // [4096][512] u32 = 8.39 MB
  unsigned* x16 = x1u + (size_t)4096 * 512;   // [4096][512] u32 = 8.39 MB

  cvt_x<<<2048, 256, 0, stream>>>(x, x16);
  combine_mfma<<<512, 256, 0, stream>>>((const _Float16*)x16, tme, Wc, bc, x1u);
  lstm_fused_mfma<<<256, 512, 0, stream>>>(x1u, Wih1, Whh1, Wih2, Whh2,
                                           bih2, bhh2, Wout, bout, outp);
}

// Round 13
// 102.288 us; speedup vs baseline: 1.2151x; 1.0033x over previous
//
#include <hip/hip_runtime.h>
#include <math.h>

// B=4096, S=128, F=8, H1=64, H2=32
// Stage 0: x16 = fp16(x); wc16 = fp16(Wc[:, :1024])   (once, ws-guarded)
// Stage A: x1u = fp16(relu(concat(x,time) @ Wc^T + bc)), fp16 MFMA, BN=64, dbuf,
//          XCD-aware block swizzle
// Stage B: fused LSTM1 || LSTM2(lag-1), 8 waves (2/SIMD), fp16 MFMA,
//          log2e-prescaled weights, fused-rcp c-update AND h-output, pkrtz.

typedef _Float16 f16x8 __attribute__((ext_vector_type(8)));
typedef float f32x4 __attribute__((ext_vector_type(4)));

union H8 { uint4 q; _Float16 h[8]; f16x8 v; };

#define MF(A, B, C) __builtin_amdgcn_mfma_f32_16x16x32_f16(A, B, C, 0, 0, 0)
#define LOG2E 1.44269504f

// fused c-update: c' = sig(yf)*c + sig(yi)*tanh(yg2/2ln2), one rcp.
__device__ __forceinline__ float lstm_c(float yi, float yf, float yg2, float cold) {
  float Ei = __builtin_amdgcn_exp2f(-yi);
  float Ef = __builtin_amdgcn_exp2f(-yf);
  float Eg = __builtin_amdgcn_exp2f(yg2);
  float Pf = 1.f + Ef;
  float t1 = (1.f + Ei) * (1.f + Eg);
  float num = fmaf(Eg - 1.f, Pf, cold * t1);
  return num * __builtin_amdgcn_rcpf(Pf * t1);
}
// fused h: sig(yo)*tanh(c) = (Ec-1) / ((Ec+1)(1+Eo)), one rcp.
__device__ __forceinline__ float lstm_h(float cc, float yo) {
  float Ec = __builtin_amdgcn_exp2f(fminf(cc * 2.88539008f, 126.f));
  float Eo = __builtin_amdgcn_exp2f(-yo);
  return (Ec - 1.f) * __builtin_amdgcn_rcpf((Ec + 1.f) * (1.f + Eo));
}
__device__ __forceinline__ unsigned pkrtz(float a, float b) {
  return __builtin_bit_cast(unsigned, __builtin_amdgcn_cvt_pkrtz(a, b));
}

// ---------------- Kernel 0a: x -> fp16, once ---------------------------------
__global__ __launch_bounds__(256) void cvt_x(
    const float* __restrict__ x, unsigned* __restrict__ x16)
{
  const int idx = blockIdx.x * 256 + threadIdx.x;  // 524288 threads, 8 f32 each
  const float4* src = (const float4*)x;
  float4 a = src[2 * idx], b = src[2 * idx + 1];
  uint4 o = {pkrtz(a.x, a.y), pkrtz(a.z, a.w), pkrtz(b.x, b.y), pkrtz(b.z, b.w)};
  ((uint4*)x16)[idx] = o;
}

// ---------------- Kernel 0b: Wc[:, :1024] -> fp16, once ----------------------
__global__ __launch_bounds__(256) void cvt_wc(
    const float* __restrict__ Wc, _Float16* __restrict__ w16)
{
  const int gid = blockIdx.x * 256 + threadIdx.x;   // 1048576 threads
  const int row = gid >> 10, col = gid & 1023;
  w16[gid] = (_Float16)Wc[(size_t)row * 1025 + col];
}

// ---------------- Kernel A: combine GEMM, fp16 MFMA, dbuf, XCD swizzle -------
// M=4096 x N=1024 x K=1024 (+time col + bias + relu). BM=128 BN=64 BK=64.
// 512 blocks 1D: xcd = bid&7 owns M-panels {4*xcd..4*xcd+3} x all 16 N-panels.
#define CROW 72  // fp16 slots per staged row (64 + 8 pad) = 144 B

template <bool W16>
__global__ __launch_bounds__(256, 2) void combine_mfma(
    const _Float16* __restrict__ xh, const float* __restrict__ tme,
    const float* __restrict__ Wc, const _Float16* __restrict__ wch,
    const float* __restrict__ bc, unsigned* __restrict__ x1u)
{
  __shared__ __align__(16) _Float16 sA[2][128][CROW];  // 36864 B
  __shared__ __align__(16) _Float16 sB[2][64][CROW];   // 18432 B
  __shared__ float sT[128];
  __shared__ float sWl[64];
  __shared__ float sBc[64];
  _Float16 (*Cst)[CROW] = sA[0];  // epilogue overlay

  const int tid = threadIdx.x;
  const int lane = tid & 63;
  const int w = tid >> 6;
  const int r = lane & 15, grp = lane >> 4;
  const int bid = blockIdx.x;
  const int xcd = bid & 7, jb = bid >> 3;
  const int M0 = (xcd * 4 + (jb & 3)) * 128;   // M-panel 0..31
  const int N0 = (jb >> 2) * 64;               // N-panel 0..15

  if (tid < 128) sT[tid] = tme[M0 + tid];
  else if (tid < 192) sWl[tid - 128] = Wc[(size_t)(N0 + tid - 128) * 1025 + 1024];
  else sBc[tid - 192] = bc[N0 + tid - 192];

#define STAGE_A(KT, BUF)                                                       \
  _Pragma("unroll") for (int i = 0; i < 4; ++i) {                              \
    int idx = tid + i * 256;                                                   \
    int row = idx >> 3, kq = idx & 7;                                          \
    uint4 v = *(const uint4*)&xh[(size_t)(M0 + row) * 1024 + (KT) + kq * 8];   \
    *(uint4*)&sA[BUF][row][kq * 8] = v;                                        \
  }
#define STAGE_B(KT, BUF)                                                       \
  if (W16) {                                                                   \
    _Pragma("unroll") for (int i = 0; i < 2; ++i) {                            \
      int idx = tid + i * 256;                                                 \
      int row = idx >> 3, kq = idx & 7;                                        \
      uint4 v = *(const uint4*)&wch[(size_t)(N0 + row) * 1024 + (KT) + kq * 8];\
      *(uint4*)&sB[BUF][row][kq * 8] = v;                                      \
    }                                                                          \
  } else {                                                                     \
    _Pragma("unroll") for (int i = 0; i < 4; ++i) {                            \
      int idx = tid + i * 256;                                                 \
      int row = idx >> 4, kq = idx & 15;                                       \
      float4 v = *(const float4*)&Wc[(size_t)(N0 + row) * 1025 + (KT) + kq * 4];\
      *(uint2*)&sB[BUF][row][kq * 4] = uint2{pkrtz(v.x, v.y), pkrtz(v.z, v.w)};\
    }                                                                          \
  }

  f32x4 acc[2][4];
#pragma unroll
  for (int i = 0; i < 2; ++i)
#pragma unroll
    for (int j2 = 0; j2 < 4; ++j2) acc[i][j2] = f32x4{0.f, 0.f, 0.f, 0.f};

  STAGE_A(0, 0);
  STAGE_B(0, 0);
  __syncthreads();

  int cur = 0;
  for (int kt = 0; kt < 1024; kt += 64) {
    H8 af[2][2], bf[4][2];
#pragma unroll
    for (int i = 0; i < 2; ++i)
#pragma unroll
      for (int c = 0; c < 2; ++c)
        af[i][c].q = *(const uint4*)&sA[cur][w * 32 + i * 16 + r][c * 32 + grp * 8];
#pragma unroll
    for (int j2 = 0; j2 < 4; ++j2)
#pragma unroll
      for (int c = 0; c < 2; ++c)
        bf[j2][c].q = *(const uint4*)&sB[cur][j2 * 16 + r][c * 32 + grp * 8];

    if (kt < 960) {
      STAGE_A(kt + 64, cur ^ 1);
      STAGE_B(kt + 64, cur ^ 1);
    }

#pragma unroll
    for (int i = 0; i < 2; ++i)
#pragma unroll
      for (int j2 = 0; j2 < 4; ++j2) {
        acc[i][j2] = MF(af[i][0].v, bf[j2][0].v, acc[i][j2]);
        acc[i][j2] = MF(af[i][1].v, bf[j2][1].v, acc[i][j2]);
      }
    __syncthreads();
    cur ^= 1;
  }
#undef STAGE_A
#undef STAGE_B

  // epilogue: time col + bias + relu -> fp16 -> LDS transpose -> coalesced store
#pragma unroll
  for (int i = 0; i < 2; ++i) {
#pragma unroll
    for (int j2 = 0; j2 < 4; ++j2) {
      int n = j2 * 16 + r;
      float wl = sWl[n], bv = sBc[n];
#pragma unroll
      for (int q = 0; q < 4; ++q) {
        int mm = w * 32 + i * 16 + 4 * grp + q;
        float v = acc[i][j2][q] + sT[mm] * wl + bv;
        Cst[mm][n] = (_Float16)fmaxf(v, 0.f);
      }
    }
  }
  __syncthreads();
#pragma unroll
  for (int i = 0; i < 4; ++i) {   // 128 rows x 8 uint4 = 1024 uint4
    int idx = tid + i * 256;
    int row = idx >> 3, c8 = idx & 7;
    uint4 v = *(const uint4*)&Cst[row][c8 * 8];
    *(uint4*)&x1u[(size_t)(M0 + row) * 512 + (N0 >> 1) + c8 * 4] = v;
  }
}

// ---------------- Kernel B: fused LSTM fp16, 8 waves, lag-1 L2 --------------
// wave w: vw = w>>1, wsub = w&1.
// L1: tiles jj=0,1 -> h1 = vw*16 + 4*grp + 2*wsub + jj.
// L2: tile u = 2*vw + wsub -> h2 = 4*u + grp.
#define ROW1 72   // shorts per sh1 row: 64 h1 slots + 8 pad
#define ROW2 40   // shorts per sh2 row: 32 h2 slots + 8 pad

__global__ __launch_bounds__(512, 2) void lstm_fused_mfma(
    const unsigned* __restrict__ x1u,
    const float* __restrict__ Wih1, const float* __restrict__ Whh1,
    const float* __restrict__ Wih2, const float* __restrict__ Whh2,
    const float* __restrict__ bih2, const float* __restrict__ bhh2,
    const float* __restrict__ Wout, const float* __restrict__ bout,
    float* __restrict__ out)
{
  __shared__ __align__(16) unsigned sxw[128 * 16 * 4];       // fp16 x [t][b][4u32] 32KB
  __shared__ float sWoT[32 * 132];                           // Wout^T [h2][t+pad] 16896B
  __shared__ __align__(16) unsigned short sh1[2][16][ROW1];  // 4608B
  __shared__ __align__(16) unsigned short sh2[2][16][ROW2];  // 2560B
  __shared__ float sOut[8][16];

  const int tid = threadIdx.x;
  const int lane = tid & 63;
  const int w = tid >> 6;       // wave 0..7
  const int vw = w >> 1;
  const int wsub = w & 1;
  const int col = lane & 15;    // A-row at pack time / batch col at run time
  const int grp = lane >> 4;    // k-slot group; C rows 4*grp+r (r = gate)
  const int b0 = blockIdx.x * 16;

  // ---- pack fp16 A-side weight fragments (once) ----
  // gate rows: i,f,o scaled by log2e; g-gate rows by 2*log2e.
  const int m1 = col >> 2, g1 = col & 3;  // A row = 4*m + gate
  const float gsc = (g1 == 2) ? 2.f * LOG2E : LOG2E;
  f16x8 A1h[2][2];  // L1 tiles jj: Whh1 chunks c=0,1 (k=64)
  f16x8 A1x[2];     // L1 tiles jj: Wih1 chunk (8 of 32 k-slots)
#pragma unroll
  for (int jj = 0; jj < 2; ++jj) {
    const int wr = g1 * 64 + vw * 16 + 4 * m1 + (2 * wsub + jj);
#pragma unroll
    for (int c = 0; c < 2; ++c) {
      H8 f;
#pragma unroll
      for (int q = 0; q < 8; ++q)
        f.h[q] = (_Float16)(Whh1[wr * 64 + c * 32 + grp * 8 + q] * gsc);
      A1h[jj][c] = f.v;
    }
    H8 fx;
#pragma unroll
    for (int q = 0; q < 8; ++q)
      fx.h[q] = (grp == 0) ? (_Float16)(Wih1[wr * 8 + q] * gsc) : (_Float16)0.f;
    A1x[jj] = fx.v;
  }
  f16x8 A2[3];  // L2: c0,c1 = Wih2 (k=64), c2 = Whh2 (k=32)
  const int u = 2 * vw + wsub;
  {
    const int wr = g1 * 32 + 4 * u + m1;
#pragma unroll
    for (int c = 0; c < 3; ++c) {
      H8 f;
#pragma unroll
      for (int q = 0; q < 8; ++q) {
        float wv = (c < 2) ? Wih2[wr * 64 + c * 32 + grp * 8 + q]
                           : Whh2[wr * 32 + grp * 8 + q];
        f.h[q] = (_Float16)(wv * gsc);
      }
      A2[c] = f.v;
    }
  }
  const int h2o = 4 * u + grp;
  f32x4 b2q;
#pragma unroll
  for (int r = 0; r < 4; ++r) {
    const float rs = (r == 2) ? 2.f * LOG2E : LOG2E;
    b2q[r] = (bih2[r * 32 + h2o] + bhh2[r * 32 + h2o]) * rs;
  }
  const f32x4 zq = {0.f, 0.f, 0.f, 0.f};

  // ---- LDS init ----
  for (int idx = tid; idx < 4096; idx += 512) {  // Wout -> [h2][t], stride 132
    int t = idx >> 5, h = idx & 31;
    sWoT[h * 132 + t] = Wout[idx];
  }
  {
    unsigned short* z = &sh1[0][0][0];
    for (int i2 = tid; i2 < 2 * 16 * ROW1; i2 += 512) z[i2] = 0;
    unsigned short* z2 = &sh2[0][0][0];
    for (int i2 = tid; i2 < 2 * 16 * ROW2; i2 += 512) z2[i2] = 0;
  }
  for (int idx = tid; idx < 16 * 512; idx += 512) {  // x preload: [t][b][4u32]
    int bb = idx >> 9, rem = idx & 511;
    int t = rem >> 2, pr = rem & 3;
    sxw[t * 64 + bb * 4 + pr] = x1u[(size_t)(b0 + bb) * 512 + rem];
  }
  __syncthreads();

  float c1a = 0.f, c1b = 0.f, c2 = 0.f, accO = 0.f;

#define PHASE(T, CUR, DO_L1, DO_L2)                                            \
  {                                                                            \
    H8 s0, s1, s2;                                                             \
    s0.q = *(const uint4*)&sh1[CUR][col][grp * 8];                             \
    s1.q = *(const uint4*)&sh1[CUR][col][32 + grp * 8];                        \
    s2.q = *(const uint4*)&sh2[CUR][col][grp * 8];                             \
    if (DO_L2) {                                                               \
      const float won = sWoT[h2o * 132 + (T) - 1];                             \
      f32x4 a = MF(A2[2], s2.v, b2q);                                          \
      a = MF(A2[0], s0.v, a);                                                  \
      a = MF(A2[1], s1.v, a);                                                  \
      float cc = lstm_c(a[0], a[1], a[2], c2);                                 \
      c2 = cc;                                                                 \
      float hn = lstm_h(cc, a[3]);                                             \
      accO = fmaf(hn, won, accO);                                              \
      *(_Float16*)&sh2[(CUR) ^ 1][col][h2o] = (_Float16)hn;                    \
    }                                                                          \
    if (DO_L1) {                                                               \
      H8 sx;                                                                   \
      sx.q = *(const uint4*)&sxw[(T) * 64 + col * 4];                          \
      f32x4 a0 = MF(A1x[0], sx.v, zq);                                         \
      f32x4 a1 = MF(A1x[1], sx.v, zq);                                         \
      a0 = MF(A1h[0][0], s0.v, a0);                                            \
      a1 = MF(A1h[1][0], s0.v, a1);                                            \
      a0 = MF(A1h[0][1], s1.v, a0);                                            \
      a1 = MF(A1h[1][1], s1.v, a1);                                            \
      float cc0 = lstm_c(a0[0], a0[1], a0[2], c1a);                            \
      c1a = cc0;                                                               \
      float h0 = lstm_h(cc0, a0[3]);                                           \
      float cc1 = lstm_c(a1[0], a1[1], a1[2], c1b);                            \
      c1b = cc1;                                                               \
      float h1v = lstm_h(cc1, a1[3]);                                          \
      *(unsigned*)&sh1[(CUR) ^ 1][col][vw * 16 + 4 * grp + 2 * wsub] =         \
          pkrtz(h0, h1v);                                                      \
    }                                                                          \
    __syncthreads();                                                           \
  }

  PHASE(0, 0, true, false);
  PHASE(1, 1, true, true);
  for (int tt = 1; tt < 64; ++tt) {
    const int t0 = 2 * tt;
    PHASE(t0, 0, true, true);
    PHASE(t0 + 1, 1, true, true);
  }
  PHASE(128, 0, false, true);
#undef PHASE

  // ---- output reduce: over grp (16/32 shuffles) then 8 waves ----
  accO += __shfl_xor(accO, 16);
  accO += __shfl_xor(accO, 32);
  if (grp == 0) sOut[u][col] = accO;
  __syncthreads();
  if (tid < 16) {
    float s = bout[0];
#pragma unroll
    for (int q = 0; q < 8; ++q) s += sOut[q][tid];
    out[b0 + tid] = s;
  }
}

extern "C" void kernel_launch(void* const* d_in, const int* in_sizes, int n_in,
                              void* d_out, int out_size, void* d_ws, size_t ws_size,
                              hipStream_t stream) {
  const float* x    = (const float*)d_in[0];
  const float* tme  = (const float*)d_in[1];
  const float* Wc   = (const float*)d_in[2];
  const float* bc   = (const float*)d_in[3];
  const float* Wih1 = (const float*)d_in[4];
  const float* Whh1 = (const float*)d_in[5];
  const float* Wih2 = (const float*)d_in[6];
  const float* Whh2 = (const float*)d_in[7];
  const float* bih2 = (const float*)d_in[8];
  const float* bhh2 = (const float*)d_in[9];
  const float* Wout = (const float*)d_in[10];
  const float* bout = (const float*)d_in[11];
  float* outp = (float*)d_out;
  unsigned* x1u = (unsigned*)d_ws;            // [4096][512] u32 = 8.39 MB
  unsigned* x16 = x1u + (size_t)4096 * 512;   // [4096][512] u32 = 8.39 MB
  _Float16* wc16 = (_Float16*)(x16 + (size_t)4096 * 512);  // [1024][1024] = 2.10 MB

  const size_t need = (size_t)4096 * 512 * 4 * 2 + (size_t)1024 * 1024 * 2;
  const bool useW16 = (ws_size >= need);

  cvt_x<<<2048, 256, 0, stream>>>(x, x16);
  if (useW16) {
    cvt_wc<<<4096, 256, 0, stream>>>(Wc, wc16);
    combine_mfma<true><<<512, 256, 0, stream>>>((const _Float16*)x16, tme, Wc,
                                                wc16, bc, x1u);
  } else {
    combine_mfma<false><<<512, 256, 0, stream>>>((const _Float16*)x16, tme, Wc,
                                                 nullptr, bc, x1u);
  }
  lstm_fused_mfma<<<256, 512, 0, stream>>>(x1u, Wih1, Whh1, Wih2, Whh2,
                                           bih2, bhh2, Wout, bout, outp);
}

// Round 14
// 98.502 us; speedup vs baseline: 1.2618x; 1.0384x over previous
//
#include <hip/hip_runtime.h>
#include <math.h>

// B=4096, S=128, F=8, H1=64, H2=32
// Stage A: x1u = fp16(relu(concat(x,time) @ Wc^T + bc)), fp16 MFMA, BN=64,
//          double-buffered LDS, in-register f32->fp16 staging (no pre-cvt
//          kernels), XCD-aware block swizzle.
// Stage B: fused LSTM1 || LSTM2(lag-1), 8 waves (2/SIMD), fp16 MFMA,
//          log2e-prescaled weights, fused-rcp c-update AND h-output, pkrtz.

typedef _Float16 f16x8 __attribute__((ext_vector_type(8)));
typedef float f32x4 __attribute__((ext_vector_type(4)));

union H8 { uint4 q; _Float16 h[8]; f16x8 v; };

#define MF(A, B, C) __builtin_amdgcn_mfma_f32_16x16x32_f16(A, B, C, 0, 0, 0)
#define LOG2E 1.44269504f

// fused c-update: c' = sig(yf)*c + sig(yi)*tanh(yg2/2ln2), one rcp.
__device__ __forceinline__ float lstm_c(float yi, float yf, float yg2, float cold) {
  float Ei = __builtin_amdgcn_exp2f(-yi);
  float Ef = __builtin_amdgcn_exp2f(-yf);
  float Eg = __builtin_amdgcn_exp2f(yg2);
  float Pf = 1.f + Ef;
  float t1 = (1.f + Ei) * (1.f + Eg);
  float num = fmaf(Eg - 1.f, Pf, cold * t1);
  return num * __builtin_amdgcn_rcpf(Pf * t1);
}
// fused h: sig(yo)*tanh(c) = (Ec-1) / ((Ec+1)(1+Eo)), one rcp.
__device__ __forceinline__ float lstm_h(float cc, float yo) {
  float Ec = __builtin_amdgcn_exp2f(fminf(cc * 2.88539008f, 126.f));
  float Eo = __builtin_amdgcn_exp2f(-yo);
  return (Ec - 1.f) * __builtin_amdgcn_rcpf((Ec + 1.f) * (1.f + Eo));
}
__device__ __forceinline__ unsigned pkrtz(float a, float b) {
  return __builtin_bit_cast(unsigned, __builtin_amdgcn_cvt_pkrtz(a, b));
}

// ---------------- Kernel A: combine GEMM, fp16 MFMA, dbuf, XCD swizzle -------
// M=4096 x N=1024 x K=1024 (+time col + bias + relu). BM=128 BN=64 BK=64.
// 512 blocks 1D: xcd = bid&7 owns M-panels {4*xcd..4*xcd+3} x all 16 N-panels.
#define CROW 72  // fp16 slots per staged row (64 + 8 pad) = 144 B

__global__ __launch_bounds__(256, 2) void combine_mfma(
    const float* __restrict__ x, const float* __restrict__ tme,
    const float* __restrict__ Wc, const float* __restrict__ bc,
    unsigned* __restrict__ x1u)   // fp16 pairs: [4096][512] u32
{
  __shared__ __align__(16) _Float16 sA[2][128][CROW];  // 36864 B
  __shared__ __align__(16) _Float16 sB[2][64][CROW];   // 18432 B
  __shared__ float sT[128];
  __shared__ float sWl[64];
  __shared__ float sBc[64];
  _Float16 (*Cst)[CROW] = sA[0];  // epilogue overlay

  const int tid = threadIdx.x;
  const int lane = tid & 63;
  const int w = tid >> 6;
  const int r = lane & 15, grp = lane >> 4;
  const int bid = blockIdx.x;
  const int xcd = bid & 7, jb = bid >> 3;
  const int M0 = (xcd * 4 + (jb & 3)) * 128;   // M-panel 0..31
  const int N0 = (jb >> 2) * 64;               // N-panel 0..15

  if (tid < 128) sT[tid] = tme[M0 + tid];
  else if (tid < 192) sWl[tid - 128] = Wc[(size_t)(N0 + tid - 128) * 1025 + 1024];
  else sBc[tid - 192] = bc[N0 + tid - 192];

  // in-register f32 -> fp16 staging (pkrtz), 8 float4 (A) + 4 float4 (B)
#define STAGE_A(KT, BUF)                                                       \
  _Pragma("unroll") for (int i = 0; i < 8; ++i) {                              \
    int idx = tid + i * 256;                                                   \
    int row = idx >> 4, kq = idx & 15;                                         \
    float4 v = *(const float4*)&x[(size_t)(M0 + row) * 1024 + (KT) + kq * 4];  \
    *(uint2*)&sA[BUF][row][kq * 4] = uint2{pkrtz(v.x, v.y), pkrtz(v.z, v.w)};  \
  }
#define STAGE_B(KT, BUF)                                                       \
  _Pragma("unroll") for (int i = 0; i < 4; ++i) {                              \
    int idx = tid + i * 256;                                                   \
    int row = idx >> 4, kq = idx & 15;                                         \
    float4 v = *(const float4*)&Wc[(size_t)(N0 + row) * 1025 + (KT) + kq * 4]; \
    *(uint2*)&sB[BUF][row][kq * 4] = uint2{pkrtz(v.x, v.y), pkrtz(v.z, v.w)};  \
  }

  f32x4 acc[2][4];
#pragma unroll
  for (int i = 0; i < 2; ++i)
#pragma unroll
    for (int j2 = 0; j2 < 4; ++j2) acc[i][j2] = f32x4{0.f, 0.f, 0.f, 0.f};

  STAGE_A(0, 0);
  STAGE_B(0, 0);
  __syncthreads();

  int cur = 0;
  for (int kt = 0; kt < 1024; kt += 64) {
    H8 af[2][2], bf[4][2];
#pragma unroll
    for (int i = 0; i < 2; ++i)
#pragma unroll
      for (int c = 0; c < 2; ++c)
        af[i][c].q = *(const uint4*)&sA[cur][w * 32 + i * 16 + r][c * 32 + grp * 8];
#pragma unroll
    for (int j2 = 0; j2 < 4; ++j2)
#pragma unroll
      for (int c = 0; c < 2; ++c)
        bf[j2][c].q = *(const uint4*)&sB[cur][j2 * 16 + r][c * 32 + grp * 8];

    if (kt < 960) {
      STAGE_A(kt + 64, cur ^ 1);
      STAGE_B(kt + 64, cur ^ 1);
    }

#pragma unroll
    for (int i = 0; i < 2; ++i)
#pragma unroll
      for (int j2 = 0; j2 < 4; ++j2) {
        acc[i][j2] = MF(af[i][0].v, bf[j2][0].v, acc[i][j2]);
        acc[i][j2] = MF(af[i][1].v, bf[j2][1].v, acc[i][j2]);
      }
    __syncthreads();
    cur ^= 1;
  }
#undef STAGE_A
#undef STAGE_B

  // epilogue: time col + bias + relu -> fp16 -> LDS transpose -> coalesced store
#pragma unroll
  for (int i = 0; i < 2; ++i) {
#pragma unroll
    for (int j2 = 0; j2 < 4; ++j2) {
      int n = j2 * 16 + r;
      float wl = sWl[n], bv = sBc[n];
#pragma unroll
      for (int q = 0; q < 4; ++q) {
        int mm = w * 32 + i * 16 + 4 * grp + q;
        float v = acc[i][j2][q] + sT[mm] * wl + bv;
        Cst[mm][n] = (_Float16)fmaxf(v, 0.f);
      }
    }
  }
  __syncthreads();
#pragma unroll
  for (int i = 0; i < 4; ++i) {   // 128 rows x 8 uint4 = 1024 uint4
    int idx = tid + i * 256;
    int row = idx >> 3, c8 = idx & 7;
    uint4 v = *(const uint4*)&Cst[row][c8 * 8];
    *(uint4*)&x1u[(size_t)(M0 + row) * 512 + (N0 >> 1) + c8 * 4] = v;
  }
}

// ---------------- Kernel B: fused LSTM fp16, 8 waves, lag-1 L2 --------------
// wave w: vw = w>>1, wsub = w&1.
// L1: tiles jj=0,1 -> h1 = vw*16 + 4*grp + 2*wsub + jj.
// L2: tile u = 2*vw + wsub -> h2 = 4*u + grp.
#define ROW1 72   // shorts per sh1 row: 64 h1 slots + 8 pad
#define ROW2 40   // shorts per sh2 row: 32 h2 slots + 8 pad

__global__ __launch_bounds__(512, 2) void lstm_fused_mfma(
    const unsigned* __restrict__ x1u,
    const float* __restrict__ Wih1, const float* __restrict__ Whh1,
    const float* __restrict__ Wih2, const float* __restrict__ Whh2,
    const float* __restrict__ bih2, const float* __restrict__ bhh2,
    const float* __restrict__ Wout, const float* __restrict__ bout,
    float* __restrict__ out)
{
  __shared__ __align__(16) unsigned sxw[128 * 16 * 4];       // fp16 x [t][b][4u32] 32KB
  __shared__ float sWoT[32 * 132];                           // Wout^T [h2][t+pad] 16896B
  __shared__ __align__(16) unsigned short sh1[2][16][ROW1];  // 4608B
  __shared__ __align__(16) unsigned short sh2[2][16][ROW2];  // 2560B
  __shared__ float sOut[8][16];

  const int tid = threadIdx.x;
  const int lane = tid & 63;
  const int w = tid >> 6;       // wave 0..7
  const int vw = w >> 1;
  const int wsub = w & 1;
  const int col = lane & 15;    // A-row at pack time / batch col at run time
  const int grp = lane >> 4;    // k-slot group; C rows 4*grp+r (r = gate)
  const int b0 = blockIdx.x * 16;

  // ---- pack fp16 A-side weight fragments (once) ----
  // gate rows: i,f,o scaled by log2e; g-gate rows by 2*log2e.
  const int m1 = col >> 2, g1 = col & 3;  // A row = 4*m + gate
  const float gsc = (g1 == 2) ? 2.f * LOG2E : LOG2E;
  f16x8 A1h[2][2];  // L1 tiles jj: Whh1 chunks c=0,1 (k=64)
  f16x8 A1x[2];     // L1 tiles jj: Wih1 chunk (8 of 32 k-slots)
#pragma unroll
  for (int jj = 0; jj < 2; ++jj) {
    const int wr = g1 * 64 + vw * 16 + 4 * m1 + (2 * wsub + jj);
#pragma unroll
    for (int c = 0; c < 2; ++c) {
      H8 f;
#pragma unroll
      for (int q = 0; q < 8; ++q)
        f.h[q] = (_Float16)(Whh1[wr * 64 + c * 32 + grp * 8 + q] * gsc);
      A1h[jj][c] = f.v;
    }
    H8 fx;
#pragma unroll
    for (int q = 0; q < 8; ++q)
      fx.h[q] = (grp == 0) ? (_Float16)(Wih1[wr * 8 + q] * gsc) : (_Float16)0.f;
    A1x[jj] = fx.v;
  }
  f16x8 A2[3];  // L2: c0,c1 = Wih2 (k=64), c2 = Whh2 (k=32)
  const int u = 2 * vw + wsub;
  {
    const int wr = g1 * 32 + 4 * u + m1;
#pragma unroll
    for (int c = 0; c < 3; ++c) {
      H8 f;
#pragma unroll
      for (int q = 0; q < 8; ++q) {
        float wv = (c < 2) ? Wih2[wr * 64 + c * 32 + grp * 8 + q]
                           : Whh2[wr * 32 + grp * 8 + q];
        f.h[q] = (_Float16)(wv * gsc);
      }
      A2[c] = f.v;
    }
  }
  const int h2o = 4 * u + grp;
  f32x4 b2q;
#pragma unroll
  for (int r = 0; r < 4; ++r) {
    const float rs = (r == 2) ? 2.f * LOG2E : LOG2E;
    b2q[r] = (bih2[r * 32 + h2o] + bhh2[r * 32 + h2o]) * rs;
  }
  const f32x4 zq = {0.f, 0.f, 0.f, 0.f};

  // ---- LDS init ----
  for (int idx = tid; idx < 4096; idx += 512) {  // Wout -> [h2][t], stride 132
    int t = idx >> 5, h = idx & 31;
    sWoT[h * 132 + t] = Wout[idx];
  }
  {
    unsigned short* z = &sh1[0][0][0];
    for (int i2 = tid; i2 < 2 * 16 * ROW1; i2 += 512) z[i2] = 0;
    unsigned short* z2 = &sh2[0][0][0];
    for (int i2 = tid; i2 < 2 * 16 * ROW2; i2 += 512) z2[i2] = 0;
  }
  for (int idx = tid; idx < 16 * 512; idx += 512) {  // x preload: [t][b][4u32]
    int bb = idx >> 9, rem = idx & 511;
    int t = rem >> 2, pr = rem & 3;
    sxw[t * 64 + bb * 4 + pr] = x1u[(size_t)(b0 + bb) * 512 + rem];
  }
  __syncthreads();

  float c1a = 0.f, c1b = 0.f, c2 = 0.f, accO = 0.f;

#define PHASE(T, CUR, DO_L1, DO_L2)                                            \
  {                                                                            \
    H8 s0, s1, s2;                                                             \
    s0.q = *(const uint4*)&sh1[CUR][col][grp * 8];                             \
    s1.q = *(const uint4*)&sh1[CUR][col][32 + grp * 8];                        \
    s2.q = *(const uint4*)&sh2[CUR][col][grp * 8];                             \
    if (DO_L2) {                                                               \
      const float won = sWoT[h2o * 132 + (T) - 1];                             \
      f32x4 a = MF(A2[2], s2.v, b2q);                                          \
      a = MF(A2[0], s0.v, a);                                                  \
      a = MF(A2[1], s1.v, a);                                                  \
      float cc = lstm_c(a[0], a[1], a[2], c2);                                 \
      c2 = cc;                                                                 \
      float hn = lstm_h(cc, a[3]);                                             \
      accO = fmaf(hn, won, accO);                                              \
      *(_Float16*)&sh2[(CUR) ^ 1][col][h2o] = (_Float16)hn;                    \
    }                                                                          \
    if (DO_L1) {                                                               \
      H8 sx;                                                                   \
      sx.q = *(const uint4*)&sxw[(T) * 64 + col * 4];                          \
      f32x4 a0 = MF(A1x[0], sx.v, zq);                                         \
      f32x4 a1 = MF(A1x[1], sx.v, zq);                                         \
      a0 = MF(A1h[0][0], s0.v, a0);                                            \
      a1 = MF(A1h[1][0], s0.v, a1);                                            \
      a0 = MF(A1h[0][1], s1.v, a0);                                            \
      a1 = MF(A1h[1][1], s1.v, a1);                                            \
      float cc0 = lstm_c(a0[0], a0[1], a0[2], c1a);                            \
      c1a = cc0;                                                               \
      float h0 = lstm_h(cc0, a0[3]);                                           \
      float cc1 = lstm_c(a1[0], a1[1], a1[2], c1b);                            \
      c1b = cc1;                                                               \
      float h1v = lstm_h(cc1, a1[3]);                                          \
      *(unsigned*)&sh1[(CUR) ^ 1][col][vw * 16 + 4 * grp + 2 * wsub] =         \
          pkrtz(h0, h1v);                                                      \
    }                                                                          \
    __syncthreads();                                                           \
  }

  PHASE(0, 0, true, false);
  PHASE(1, 1, true, true);
  for (int tt = 1; tt < 64; ++tt) {
    const int t0 = 2 * tt;
    PHASE(t0, 0, true, true);
    PHASE(t0 + 1, 1, true, true);
  }
  PHASE(128, 0, false, true);
#undef PHASE

  // ---- output reduce: over grp (16/32 shuffles) then 8 waves ----
  accO += __shfl_xor(accO, 16);
  accO += __shfl_xor(accO, 32);
  if (grp == 0) sOut[u][col] = accO;
  __syncthreads();
  if (tid < 16) {
    float s = bout[0];
#pragma unroll
    for (int q = 0; q < 8; ++q) s += sOut[q][tid];
    out[b0 + tid] = s;
  }
}

extern "C" void kernel_launch(void* const* d_in, const int* in_sizes, int n_in,
                              void* d_out, int out_size, void* d_ws, size_t ws_size,
                              hipStream_t stream) {
  const float* x    = (const float*)d_in[0];
  const float* tme  = (const float*)d_in[1];
  const float* Wc   = (const float*)d_in[2];
  const float* bc   = (const float*)d_in[3];
  const float* Wih1 = (const float*)d_in[4];
  const float* Whh1 = (const float*)d_in[5];
  const float* Wih2 = (const float*)d_in[6];
  const float* Whh2 = (const float*)d_in[7];
  const float* bih2 = (const float*)d_in[8];
  const float* bhh2 = (const float*)d_in[9];
  const float* Wout = (const float*)d_in[10];
  const float* bout = (const float*)d_in[11];
  float* outp = (float*)d_out;
  unsigned* x1u = (unsigned*)d_ws;  // [4096][512] fp16-pair u32 = 8.39 MB

  combine_mfma<<<512, 256, 0, stream>>>(x, tme, Wc, bc, x1u);
  lstm_fused_mfma<<<256, 512, 0, stream>>>(x1u, Wih1, Whh1, Wih2, Whh2,
                                           bih2, bhh2, Wout, bout, outp);
}